// Round 26
// baseline (116.019 us; speedup 1.0000x reference)
//
#include <hip/hip_runtime.h>
#include <math.h>

// Problem constants: B=2, T=2048, C=1024, H=16, D=64
constexpr int Bb = 2;
constexpr int Tt = 2048;
constexpr int Cc = 1024;
constexpr int Hh = 16;
constexpr int M_ROWS = Bb * Tt;          // 4096
constexpr float EPSV = 1e-5f;

typedef __attribute__((ext_vector_type(4))) float f32x4;
typedef __attribute__((ext_vector_type(8))) __bf16 bf16x8;
using u16 = unsigned short;

union Frag8 {
    u16 u[8];
    unsigned int ui[4];
    uint4 v;
    bf16x8 b;
};

// fp32 -> bf16 round-to-nearest-even
__device__ __forceinline__ u16 f2bf(float f) {
    union { float f; unsigned int u; } c;
    c.f = f;
    unsigned int r = (c.u + 0x7fffu + ((c.u >> 16) & 1u)) >> 16;
    return (u16)r;
}
__device__ __forceinline__ float bf2f(u16 u) {
    union { unsigned int i; float f; } c;
    c.i = ((unsigned int)u) << 16;
    return c.f;
}

// async global->LDS, 16 B per lane; LDS dest = wave-uniform base + lane*16
__device__ __forceinline__ void gload_lds16(const void* g, void* l) {
    __builtin_amdgcn_global_load_lds(
        (__attribute__((address_space(1))) void*)const_cast<void*>(g),
        (__attribute__((address_space(3))) void*)l, 16, 0, 0);
}

// ---------------------------------------------------------------------------
// Prep (merged): weight bf16 converts + RoPE tables [T][32] + RMSNorm.
// Grid 8448 x 256: [0,3072) w_qkv, [3072,4096) w_o, [4096,4352) tables,
// [4352,8448) rmsnorm (one block per row).
// ---------------------------------------------------------------------------
__global__ __launch_bounds__(256) void prep_k(const float* __restrict__ w_qkv,
                                              u16* __restrict__ wqkv_bf,
                                              const float* __restrict__ w_o,
                                              u16* __restrict__ wo_bf,
                                              float* __restrict__ cosT,
                                              float* __restrict__ sinT,
                                              const float* __restrict__ x,
                                              const float* __restrict__ rms_w,
                                              u16* __restrict__ xn) {
    __shared__ float ws_[4];
    int blk = blockIdx.x;
    int tid = threadIdx.x;
    if (blk < 3072) {
        int i = (blk * 256 + tid) * 4;
        float4 v = *(const float4*)&w_qkv[i];
        ushort4 o;
        o.x = f2bf(v.x); o.y = f2bf(v.y); o.z = f2bf(v.z); o.w = f2bf(v.w);
        *(ushort4*)&wqkv_bf[i] = o;
    } else if (blk < 4096) {
        int i = ((blk - 3072) * 256 + tid) * 4;
        float4 v = *(const float4*)&w_o[i];
        ushort4 o;
        o.x = f2bf(v.x); o.y = f2bf(v.y); o.z = f2bf(v.z); o.w = f2bf(v.w);
        *(ushort4*)&wo_bf[i] = o;
    } else if (blk < 4352) {
        int lin = (blk - 4096) * 256 + tid;   // 0..65535 = t*32+j
        int tt = lin >> 5, j = lin & 31;
        float inv = exp2f(-(float)j * (log2f(10000.0f) / 32.0f));
        float a = (float)tt * inv;
        cosT[lin] = cosf(a);
        sinT[lin] = sinf(a);
    } else {
        int row = blk - 4352;
        const float* xr = x + (size_t)row * Cc;
        float4 v = *(const float4*)&xr[tid * 4];
        float ss = v.x * v.x + v.y * v.y + v.z * v.z + v.w * v.w;
        #pragma unroll
        for (int off = 32; off > 0; off >>= 1) ss += __shfl_down(ss, off);
        if ((tid & 63) == 0) ws_[tid >> 6] = ss;
        __syncthreads();
        float tot = ws_[0] + ws_[1] + ws_[2] + ws_[3];
        float r = rsqrtf(tot * (1.0f / (float)Cc) + EPSV);
        float4 wv = *(const float4*)&rms_w[tid * 4];
        ushort4 o;
        o.x = f2bf(v.x * r * wv.x);
        o.y = f2bf(v.y * r * wv.y);
        o.z = f2bf(v.z * r * wv.z);
        o.w = f2bf(v.w * r * wv.w);
        *(ushort4*)&xn[(size_t)row * Cc + tid * 4] = o;
    }
}

// ---------------------------------------------------------------------------
// bf16 MFMA GEMM v2 (R19 winner): 128x64 tile, BK=64, 4 waves, 24KB LDS ->
// 6 blocks/CU. 2-barrier skeleton + source-chunk XOR swizzle (rule #21).
// ---------------------------------------------------------------------------
template<bool BF16OUT>
__global__ __launch_bounds__(256) void gemm_mfma_k(const u16* __restrict__ A,
                                                   const u16* __restrict__ W,
                                                   const float* __restrict__ bias,
                                                   void* __restrict__ Ov,
                                                   int M, int N, int K) {
    __shared__ __align__(16) u16 As[128 * 64];   // 16 KB
    __shared__ __align__(16) u16 Bs[64 * 64];    // 8 KB

    const int tid = threadIdx.x;
    const int w = tid >> 6;
    const int l = tid & 63;
    const int wr = w >> 1;
    const int wc = w & 1;
    const int q = l & 15;
    const int g = l >> 4;

    const int m0 = blockIdx.y * 128;
    const int n0 = blockIdx.x * 64;

    const int srow = l >> 3;
    const int cph = l & 7;
    const int cl = cph ^ srow;

    f32x4 acc[4][2];
    #pragma unroll
    for (int i = 0; i < 4; ++i)
        #pragma unroll
        for (int j = 0; j < 2; ++j)
            acc[i][j] = (f32x4){0.f, 0.f, 0.f, 0.f};

    const int nkt = K >> 6;
    for (int kt = 0; kt < nkt; ++kt) {
        const int k0 = kt << 6;
        __syncthreads();
        #pragma unroll
        for (int iss = 0; iss < 4; ++iss) {
            int r = w * 32 + iss * 8 + srow;
            gload_lds16(A + (size_t)(m0 + r) * K + k0 + cl * 8,
                        &As[(w * 32 + iss * 8) * 64]);
        }
        #pragma unroll
        for (int iss = 0; iss < 2; ++iss) {
            int r = w * 16 + iss * 8 + srow;
            gload_lds16(W + (size_t)(n0 + r) * K + k0 + cl * 8,
                        &Bs[(w * 16 + iss * 8) * 64]);
        }
        __syncthreads();

        #pragma unroll
        for (int kk = 0; kk < 2; ++kk) {
            Frag8 af[4], bf[2];
            const int ca = kk * 4 + g;
            #pragma unroll
            for (int i = 0; i < 4; ++i) {
                int ra = wr * 64 + i * 16 + q;
                af[i] = *(const Frag8*)&As[ra * 64 + ((ca ^ (ra & 7)) * 8)];
            }
            #pragma unroll
            for (int j = 0; j < 2; ++j) {
                int rb = wc * 32 + j * 16 + q;
                bf[j] = *(const Frag8*)&Bs[rb * 64 + ((ca ^ (rb & 7)) * 8)];
            }
            #pragma unroll
            for (int i = 0; i < 4; ++i)
                #pragma unroll
                for (int j = 0; j < 2; ++j)
                    acc[i][j] = __builtin_amdgcn_mfma_f32_16x16x32_bf16(
                        af[i].b, bf[j].b, acc[i][j], 0, 0, 0);
        }
    }

    #pragma unroll
    for (int i = 0; i < 4; ++i) {
        int row = m0 + wr * 64 + i * 16 + g * 4;
        #pragma unroll
        for (int j = 0; j < 2; ++j) {
            int col = n0 + wc * 32 + j * 16 + q;
            float bb = bias[col];
            #pragma unroll
            for (int r2 = 0; r2 < 4; ++r2) {
                float val = acc[i][j][r2] + bb;
                if (BF16OUT)
                    ((u16*)Ov)[(size_t)(row + r2) * N + col] = f2bf(val);
                else
                    ((float*)Ov)[(size_t)(row + r2) * N + col] = val;
            }
        }
    }
}

// ---------------------------------------------------------------------------
// RoPE + repack v2 (unchanged R24/25): qkv_bf16 [b,t,3,h,64] ->
//   Qb [bh][t][64] bf16 (Q pre-scaled by 0.125*log2e)
//   KL [bh][tile][kk*4+g][lane][8] bf16  -- fragment-major
//   VL [bh][tile][kk*4+dg][lane][8] bf16 -- fragment-major, pi folded in
// ---------------------------------------------------------------------------
__global__ __launch_bounds__(256) void rope_pack_k(const u16* __restrict__ qkv,
                                                   const float* __restrict__ cosT,
                                                   const float* __restrict__ sinT,
                                                   u16* __restrict__ Qb,
                                                   u16* __restrict__ KL,
                                                   u16* __restrict__ VL) {
    const int jt = blockIdx.x;          // tile 0..31
    const int t0 = jt * 64;
    const int h = blockIdx.y, b = blockIdx.z;
    const int t = threadIdx.x;
    const int bh = b * Hh + h;
    __shared__ u16 Vs[64 * 64];
    constexpr float QSC = 0.125f * 1.44269504089f;   // 1/sqrt(D) * log2(e)
    const size_t tilebase = ((size_t)bh * 32 + jt) * 4096;

    {
        int row = t >> 2, d16 = (t & 3) * 16;
        const u16* vp = qkv + (size_t)(b * Tt + t0 + row) * 3072 + 2048 + h * 64 + d16;
        *(uint4*)&Vs[row * 64 + d16]     = *(const uint4*)vp;
        *(uint4*)&Vs[row * 64 + d16 + 8] = *(const uint4*)(vp + 8);
    }

    {
        int row = t >> 2, d0 = (t & 3) * 8;
        int g = row >> 4, q15 = row & 15, g2 = t & 3;
        size_t rb = (size_t)(b * Tt + t0 + row) * 3072 + h * 64;
        const u16* qp = qkv + rb;
        const u16* kp = qkv + rb + 1024;
        Frag8 qlo, qhi, klo, khi;
        qlo.v = *(const uint4*)&qp[d0];
        qhi.v = *(const uint4*)&qp[d0 + 32];
        klo.v = *(const uint4*)&kp[d0];
        khi.v = *(const uint4*)&kp[d0 + 32];
        const float* cp = &cosT[(t0 + row) * 32 + d0];
        const float* sp = &sinT[(t0 + row) * 32 + d0];
        float4 c0 = *(const float4*)cp, c1 = *(const float4*)(cp + 4);
        float4 s0 = *(const float4*)sp, s1 = *(const float4*)(sp + 4);
        float cc[8] = {c0.x, c0.y, c0.z, c0.w, c1.x, c1.y, c1.z, c1.w};
        float ss[8] = {s0.x, s0.y, s0.z, s0.w, s1.x, s1.y, s1.z, s1.w};
        Frag8 oql, oqh, okl, okh;
        #pragma unroll
        for (int i = 0; i < 8; ++i) {
            float ql = bf2f(qlo.u[i]), qh = bf2f(qhi.u[i]);
            float kl = bf2f(klo.u[i]), kh = bf2f(khi.u[i]);
            oql.u[i] = f2bf((ql * cc[i] - qh * ss[i]) * QSC);
            oqh.u[i] = f2bf((qh * cc[i] + ql * ss[i]) * QSC);
            okl.u[i] = f2bf(kl * cc[i] - kh * ss[i]);
            okh.u[i] = f2bf(kh * cc[i] + kl * ss[i]);
        }
        u16* qd = Qb + ((size_t)bh * Tt + t0 + row) * 64;
        *(uint4*)&qd[d0]      = oql.v;
        *(uint4*)&qd[d0 + 32] = oqh.v;
        *(uint4*)&KL[tilebase + (size_t)(0 * 4 + g) * 512 + (g2 * 16 + q15) * 8] = okl.v;
        *(uint4*)&KL[tilebase + (size_t)(1 * 4 + g) * 512 + (g2 * 16 + q15) * 8] = okh.v;
    }
    __syncthreads();

    {
        int d = t >> 2, kq = (t & 3) * 16;
        int dg = d >> 4, q15v = d & 15;
        int kkv = (t & 3) >> 1;
        int g2a = ((t & 3) & 1) * 2;
        Frag8 a, b2;
        #pragma unroll
        for (int j = 0; j < 16; ++j) {
            int slot = kq + j;
            int key = ((slot >> 5) * 2 + ((slot >> 2) & 1)) * 16
                    + ((slot >> 3) & 3) * 4 + (slot & 3);
            u16 vv = Vs[key * 64 + d];
            if (j < 8) a.u[j] = vv; else b2.u[j - 8] = vv;
        }
        u16* base = VL + tilebase + (size_t)(kkv * 4 + dg) * 512;
        *(uint4*)&base[(g2a * 16 + q15v) * 8]       = a.v;
        *(uint4*)&base[((g2a + 1) * 16 + q15v) * 8] = b2.v;
    }
}

// ---------------------------------------------------------------------------
// MFMA flash attention v15: zero-LDS streaming, 2x AMORTIZED. R25 diagnosis:
// v13/v14 were L2-BW-bound (each of 4 waves re-read the same 16KB fragments
// -> 1.08 GB L2 traffic ~= 31us floor). Fix: q-tile = 128 rows/block; each
// wave computes TWO 16-row groups (half A rows c*128+w4*16, half B +64)
// against each loaded fragment set -> L2 traffic halves. Causal: j=0..2c+1;
// A computes j<=2c (mask at 2c), B all j (mask at 2c+1) -- block-uniform.
// Grid 512 heavy-first (pair-sum 34 iters). launch_bounds(256,2) allows the
// ~140-VGPR live set so loads batch.
// ---------------------------------------------------------------------------
__global__ __launch_bounds__(256, 2) void attn_mfma_k(const u16* __restrict__ Qb,
                                                      const u16* __restrict__ KL,
                                                      const u16* __restrict__ VL,
                                                      u16* __restrict__ out) {
    const int i = blockIdx.x;           // 0..511
    int c, bh;
    if (i < 256) { c = 15 - (i >> 5); bh = i & 31; }        // heavy first
    else         { int k = i - 256; c = k >> 5; bh = k & 31; }
    const int b = bh >> 4, h = bh & 15;

    const int t = threadIdx.x;
    const int w4 = t >> 6;       // wave 0..3
    const int l = t & 63;
    const int q15 = l & 15;
    const int g2 = l >> 4;

    // ---- Q fragments for both halves (exp2-domain scale pre-folded) ----
    Frag8 qfA[2], qfB[2];
    {
        int qrowA = c * 128 + w4 * 16 + q15;
        const u16* qpA = Qb + ((size_t)bh * Tt + qrowA) * 64;
        qfA[0] = *(const Frag8*)&qpA[g2 * 8];
        qfA[1] = *(const Frag8*)&qpA[32 + g2 * 8];
        const u16* qpB = qpA + (size_t)64 * 64;
        qfB[0] = *(const Frag8*)&qpB[g2 * 8];
        qfB[1] = *(const Frag8*)&qpB[32 + g2 * 8];
    }

    Frag8 ones;
    #pragma unroll
    for (int e = 0; e < 8; ++e) ones.u[e] = 0x3F80;   // bf16 1.0

    f32x4 accoA[4], accoB[4];
    #pragma unroll
    for (int dg = 0; dg < 4; ++dg) {
        accoA[dg] = (f32x4){0.f, 0.f, 0.f, 0.f};
        accoB[dg] = (f32x4){0.f, 0.f, 0.f, 0.f};
    }
    f32x4 acc_lA = (f32x4){0.f, 0.f, 0.f, 0.f};
    f32x4 acc_lB = (f32x4){0.f, 0.f, 0.f, 0.f};

    // fragment-major bases; lane offset l*8 u16 = 16B, contiguous per wave.
    const u16* kp0 = KL + ((size_t)bh * 32) * 4096 + l * 8;
    const u16* kp1 = kp0 + 2048;     // frags 4..7
    const u16* vp0 = VL + ((size_t)bh * 32) * 4096 + l * 8;
    const u16* vp1 = vp0 + 2048;

    const int jdA = 2 * c;           // half A diagonal tile
    const int jmax = 2 * c + 1;      // half B diagonal tile (= last)

    for (int j = 0; j <= jmax; ++j) {
        // ---- K fragment loads (shared by both halves) ----
        Frag8 kf[2][4];
        #pragma unroll
        for (int g = 0; g < 4; ++g) {
            kf[0][g] = *(const Frag8*)&kp0[g * 512];
            kf[1][g] = *(const Frag8*)&kp1[g * 512];
        }

        // ---- QK^T both halves (independent MFMA chains) ----
        f32x4 saccA[4], saccB[4];
        __builtin_amdgcn_s_setprio(1);
        #pragma unroll
        for (int g = 0; g < 4; ++g) {
            saccA[g] = (f32x4){0.f, 0.f, 0.f, 0.f};
            saccA[g] = __builtin_amdgcn_mfma_f32_16x16x32_bf16(
                kf[0][g].b, qfA[0].b, saccA[g], 0, 0, 0);
            saccA[g] = __builtin_amdgcn_mfma_f32_16x16x32_bf16(
                kf[1][g].b, qfA[1].b, saccA[g], 0, 0, 0);
            saccB[g] = (f32x4){0.f, 0.f, 0.f, 0.f};
            saccB[g] = __builtin_amdgcn_mfma_f32_16x16x32_bf16(
                kf[0][g].b, qfB[0].b, saccB[g], 0, 0, 0);
            saccB[g] = __builtin_amdgcn_mfma_f32_16x16x32_bf16(
                kf[1][g].b, qfB[1].b, saccB[g], 0, 0, 0);
        }
        __builtin_amdgcn_s_setprio(0);

        // ---- V fragment loads (latency hides under mask+exp2 VALU) ----
        Frag8 vf[2][4];
        #pragma unroll
        for (int dg = 0; dg < 4; ++dg) {
            vf[0][dg] = *(const Frag8*)&vp0[dg * 512];
            vf[1][dg] = *(const Frag8*)&vp1[dg * 512];
        }

        // ---- causal masks (block-uniform j tests) ----
        if (j == jdA) {
            #pragma unroll
            for (int g = 0; g < 4; ++g)
                #pragma unroll
                for (int r = 0; r < 4; ++r)
                    if (g * 16 + g2 * 4 + r > w4 * 16 + q15) saccA[g][r] = -1e30f;
        }
        if (j == jmax) {
            #pragma unroll
            for (int g = 0; g < 4; ++g)
                #pragma unroll
                for (int r = 0; r < 4; ++r)
                    if (g * 16 + g2 * 4 + r > w4 * 16 + q15) saccB[g][r] = -1e30f;
        }

        // ---- half A: P=exp2(S), l-sum, PV (skip past its diagonal) ----
        if (j <= jdA) {
            Frag8 pa[2];
            #pragma unroll
            for (int kk = 0; kk < 2; ++kk)
                #pragma unroll
                for (int e = 0; e < 8; ++e)
                    pa[kk].b[e] = (__bf16)exp2f(saccA[2 * kk + (e >> 2)][e & 3]);
            __builtin_amdgcn_s_setprio(1);
            acc_lA = __builtin_amdgcn_mfma_f32_16x16x32_bf16(pa[0].b, ones.b, acc_lA, 0, 0, 0);
            acc_lA = __builtin_amdgcn_mfma_f32_16x16x32_bf16(pa[1].b, ones.b, acc_lA, 0, 0, 0);
            #pragma unroll
            for (int dg = 0; dg < 4; ++dg) {
                accoA[dg] = __builtin_amdgcn_mfma_f32_16x16x32_bf16(
                    pa[0].b, vf[0][dg].b, accoA[dg], 0, 0, 0);
                accoA[dg] = __builtin_amdgcn_mfma_f32_16x16x32_bf16(
                    pa[1].b, vf[1][dg].b, accoA[dg], 0, 0, 0);
            }
            __builtin_amdgcn_s_setprio(0);
        }

        // ---- half B: always ----
        {
            Frag8 pb[2];
            #pragma unroll
            for (int kk = 0; kk < 2; ++kk)
                #pragma unroll
                for (int e = 0; e < 8; ++e)
                    pb[kk].b[e] = (__bf16)exp2f(saccB[2 * kk + (e >> 2)][e & 3]);
            __builtin_amdgcn_s_setprio(1);
            acc_lB = __builtin_amdgcn_mfma_f32_16x16x32_bf16(pb[0].b, ones.b, acc_lB, 0, 0, 0);
            acc_lB = __builtin_amdgcn_mfma_f32_16x16x32_bf16(pb[1].b, ones.b, acc_lB, 0, 0, 0);
            #pragma unroll
            for (int dg = 0; dg < 4; ++dg) {
                accoB[dg] = __builtin_amdgcn_mfma_f32_16x16x32_bf16(
                    pb[0].b, vf[0][dg].b, accoB[dg], 0, 0, 0);
                accoB[dg] = __builtin_amdgcn_mfma_f32_16x16x32_bf16(
                    pb[1].b, vf[1][dg].b, accoB[dg], 0, 0, 0);
            }
            __builtin_amdgcn_s_setprio(0);
        }

        kp0 += 4096; kp1 += 4096;
        vp0 += 4096; vp1 += 4096;
    }

    // ---- epilogue: both halves; acc_l[r] = row sum for row g2*4+r ----
    {
        float lr[4];
        #pragma unroll
        for (int r = 0; r < 4; ++r) lr[r] = 1.f / acc_lA[r];
        const int qbase = c * 128 + w4 * 16;
        #pragma unroll
        for (int dg = 0; dg < 4; ++dg)
            #pragma unroll
            for (int r = 0; r < 4; ++r)
                out[((size_t)(b * Tt + qbase + g2 * 4 + r)) * Cc + h * 64 + dg * 16 + q15] =
                    f2bf(accoA[dg][r] * lr[r]);
    }
    {
        float lr[4];
        #pragma unroll
        for (int r = 0; r < 4; ++r) lr[r] = 1.f / acc_lB[r];
        const int qbase = c * 128 + 64 + w4 * 16;
        #pragma unroll
        for (int dg = 0; dg < 4; ++dg)
            #pragma unroll
            for (int r = 0; r < 4; ++r)
                out[((size_t)(b * Tt + qbase + g2 * 4 + r)) * Cc + h * 64 + dg * 16 + q15] =
                    f2bf(accoB[dg][r] * lr[r]);
    }
}

// ---------------------------------------------------------------------------
// Launch
// ---------------------------------------------------------------------------
extern "C" void kernel_launch(void* const* d_in, const int* in_sizes, int n_in,
                              void* d_out, int out_size, void* d_ws, size_t ws_size,
                              hipStream_t stream) {
    const float* x      = (const float*)d_in[0];
    const float* w_qkv  = (const float*)d_in[2];
    const float* b_qkv  = (const float*)d_in[3];
    const float* w_o    = (const float*)d_in[4];
    const float* b_o    = (const float*)d_in[5];
    const float* rms_w  = (const float*)d_in[6];
    float* out = (float*)d_out;

    char* ws = (char*)d_ws;
    u16*   xn_bf   = (u16*)ws;                                   // 8 MB [0,8)
    u16*   KL      = (u16*)(ws + (size_t)(8 << 20));             // 8 MB [8,16)
    u16*   VL      = (u16*)(ws + (size_t)(16 << 20));            // 8 MB [16,24)
    u16*   Qb      = (u16*)(ws + (size_t)(24 << 20));            // 8 MB [24,32)
    u16*   qkvb    = (u16*)(ws + (size_t)(32 << 20));            // 24 MB [32,56)
    u16*   wqkv_bf = (u16*)(ws + (size_t)(56 << 20));            // 6 MB [56,62)
    u16*   wo_bf   = (u16*)(ws + (size_t)(62 << 20));            // 2 MB [62,64)
    float* cosT    = (float*)(ws + (size_t)(64 << 20));          // 256 KB
    float* sinT    = (float*)(ws + (size_t)(64 << 20) + (1 << 18));
    u16*   attn_bf = xn_bf;   // xn dead after QKV GEMM

    prep_k<<<dim3(8448), dim3(256), 0, stream>>>(w_qkv, wqkv_bf, w_o, wo_bf,
                                                 cosT, sinT, x, rms_w, xn_bf);
    gemm_mfma_k<true><<<dim3(3 * Cc / 64, M_ROWS / 128), dim3(256), 0, stream>>>(
        xn_bf, wqkv_bf, b_qkv, qkvb, M_ROWS, 3 * Cc, Cc);
    rope_pack_k<<<dim3(Tt / 64, Hh, Bb), dim3(256), 0, stream>>>(
        qkvb, cosT, sinT, Qb, KL, VL);
    attn_mfma_k<<<dim3(512), dim3(256), 0, stream>>>(Qb, KL, VL, attn_bf);
    gemm_mfma_k<false><<<dim3(Cc / 64, M_ROWS / 128), dim3(256), 0, stream>>>(
        attn_bf, wo_bf, b_o, out, M_ROWS, Cc, Cc);
}

// Round 27
// 113.819 us; speedup vs baseline: 1.0193x; 1.0193x over previous
//
#include <hip/hip_runtime.h>
#include <math.h>

// Problem constants: B=2, T=2048, C=1024, H=16, D=64
constexpr int Bb = 2;
constexpr int Tt = 2048;
constexpr int Cc = 1024;
constexpr int Hh = 16;
constexpr int M_ROWS = Bb * Tt;          // 4096
constexpr float EPSV = 1e-5f;

typedef __attribute__((ext_vector_type(4))) float f32x4;
typedef __attribute__((ext_vector_type(8))) __bf16 bf16x8;
using u16 = unsigned short;

union Frag8 {
    u16 u[8];
    unsigned int ui[4];
    uint4 v;
    bf16x8 b;
};

// fp32 -> bf16 round-to-nearest-even
__device__ __forceinline__ u16 f2bf(float f) {
    union { float f; unsigned int u; } c;
    c.f = f;
    unsigned int r = (c.u + 0x7fffu + ((c.u >> 16) & 1u)) >> 16;
    return (u16)r;
}
__device__ __forceinline__ float bf2f(u16 u) {
    union { unsigned int i; float f; } c;
    c.i = ((unsigned int)u) << 16;
    return c.f;
}

// async global->LDS, 16 B per lane; LDS dest = wave-uniform base + lane*16
__device__ __forceinline__ void gload_lds16(const void* g, void* l) {
    __builtin_amdgcn_global_load_lds(
        (__attribute__((address_space(1))) void*)const_cast<void*>(g),
        (__attribute__((address_space(3))) void*)l, 16, 0, 0);
}

// ---------------------------------------------------------------------------
// Prep (merged): weight bf16 converts + RoPE tables [T][32] + RMSNorm.
// Grid 8448 x 256: [0,3072) w_qkv, [3072,4096) w_o, [4096,4352) tables,
// [4352,8448) rmsnorm (one block per row).
// ---------------------------------------------------------------------------
__global__ __launch_bounds__(256) void prep_k(const float* __restrict__ w_qkv,
                                              u16* __restrict__ wqkv_bf,
                                              const float* __restrict__ w_o,
                                              u16* __restrict__ wo_bf,
                                              float* __restrict__ cosT,
                                              float* __restrict__ sinT,
                                              const float* __restrict__ x,
                                              const float* __restrict__ rms_w,
                                              u16* __restrict__ xn) {
    __shared__ float ws_[4];
    int blk = blockIdx.x;
    int tid = threadIdx.x;
    if (blk < 3072) {
        int i = (blk * 256 + tid) * 4;
        float4 v = *(const float4*)&w_qkv[i];
        ushort4 o;
        o.x = f2bf(v.x); o.y = f2bf(v.y); o.z = f2bf(v.z); o.w = f2bf(v.w);
        *(ushort4*)&wqkv_bf[i] = o;
    } else if (blk < 4096) {
        int i = ((blk - 3072) * 256 + tid) * 4;
        float4 v = *(const float4*)&w_o[i];
        ushort4 o;
        o.x = f2bf(v.x); o.y = f2bf(v.y); o.z = f2bf(v.z); o.w = f2bf(v.w);
        *(ushort4*)&wo_bf[i] = o;
    } else if (blk < 4352) {
        int lin = (blk - 4096) * 256 + tid;   // 0..65535 = t*32+j
        int tt = lin >> 5, j = lin & 31;
        float inv = exp2f(-(float)j * (log2f(10000.0f) / 32.0f));
        float a = (float)tt * inv;
        cosT[lin] = cosf(a);
        sinT[lin] = sinf(a);
    } else {
        int row = blk - 4352;
        const float* xr = x + (size_t)row * Cc;
        float4 v = *(const float4*)&xr[tid * 4];
        float ss = v.x * v.x + v.y * v.y + v.z * v.z + v.w * v.w;
        #pragma unroll
        for (int off = 32; off > 0; off >>= 1) ss += __shfl_down(ss, off);
        if ((tid & 63) == 0) ws_[tid >> 6] = ss;
        __syncthreads();
        float tot = ws_[0] + ws_[1] + ws_[2] + ws_[3];
        float r = rsqrtf(tot * (1.0f / (float)Cc) + EPSV);
        float4 wv = *(const float4*)&rms_w[tid * 4];
        ushort4 o;
        o.x = f2bf(v.x * r * wv.x);
        o.y = f2bf(v.y * r * wv.y);
        o.z = f2bf(v.z * r * wv.z);
        o.w = f2bf(v.w * r * wv.w);
        *(ushort4*)&xn[(size_t)row * Cc + tid * 4] = o;
    }
}

// ---------------------------------------------------------------------------
// bf16 MFMA GEMM v2 (R19 winner): 128x64 tile, BK=64, 4 waves, 24KB LDS ->
// 6 blocks/CU. 2-barrier skeleton + source-chunk XOR swizzle (rule #21).
// ---------------------------------------------------------------------------
template<bool BF16OUT>
__global__ __launch_bounds__(256) void gemm_mfma_k(const u16* __restrict__ A,
                                                   const u16* __restrict__ W,
                                                   const float* __restrict__ bias,
                                                   void* __restrict__ Ov,
                                                   int M, int N, int K) {
    __shared__ __align__(16) u16 As[128 * 64];   // 16 KB
    __shared__ __align__(16) u16 Bs[64 * 64];    // 8 KB

    const int tid = threadIdx.x;
    const int w = tid >> 6;
    const int l = tid & 63;
    const int wr = w >> 1;
    const int wc = w & 1;
    const int q = l & 15;
    const int g = l >> 4;

    const int m0 = blockIdx.y * 128;
    const int n0 = blockIdx.x * 64;

    const int srow = l >> 3;
    const int cph = l & 7;
    const int cl = cph ^ srow;

    f32x4 acc[4][2];
    #pragma unroll
    for (int i = 0; i < 4; ++i)
        #pragma unroll
        for (int j = 0; j < 2; ++j)
            acc[i][j] = (f32x4){0.f, 0.f, 0.f, 0.f};

    const int nkt = K >> 6;
    for (int kt = 0; kt < nkt; ++kt) {
        const int k0 = kt << 6;
        __syncthreads();
        #pragma unroll
        for (int iss = 0; iss < 4; ++iss) {
            int r = w * 32 + iss * 8 + srow;
            gload_lds16(A + (size_t)(m0 + r) * K + k0 + cl * 8,
                        &As[(w * 32 + iss * 8) * 64]);
        }
        #pragma unroll
        for (int iss = 0; iss < 2; ++iss) {
            int r = w * 16 + iss * 8 + srow;
            gload_lds16(W + (size_t)(n0 + r) * K + k0 + cl * 8,
                        &Bs[(w * 16 + iss * 8) * 64]);
        }
        __syncthreads();

        #pragma unroll
        for (int kk = 0; kk < 2; ++kk) {
            Frag8 af[4], bf[2];
            const int ca = kk * 4 + g;
            #pragma unroll
            for (int i = 0; i < 4; ++i) {
                int ra = wr * 64 + i * 16 + q;
                af[i] = *(const Frag8*)&As[ra * 64 + ((ca ^ (ra & 7)) * 8)];
            }
            #pragma unroll
            for (int j = 0; j < 2; ++j) {
                int rb = wc * 32 + j * 16 + q;
                bf[j] = *(const Frag8*)&Bs[rb * 64 + ((ca ^ (rb & 7)) * 8)];
            }
            #pragma unroll
            for (int i = 0; i < 4; ++i)
                #pragma unroll
                for (int j = 0; j < 2; ++j)
                    acc[i][j] = __builtin_amdgcn_mfma_f32_16x16x32_bf16(
                        af[i].b, bf[j].b, acc[i][j], 0, 0, 0);
        }
    }

    #pragma unroll
    for (int i = 0; i < 4; ++i) {
        int row = m0 + wr * 64 + i * 16 + g * 4;
        #pragma unroll
        for (int j = 0; j < 2; ++j) {
            int col = n0 + wc * 32 + j * 16 + q;
            float bb = bias[col];
            #pragma unroll
            for (int r2 = 0; r2 < 4; ++r2) {
                float val = acc[i][j][r2] + bb;
                if (BF16OUT)
                    ((u16*)Ov)[(size_t)(row + r2) * N + col] = f2bf(val);
                else
                    ((float*)Ov)[(size_t)(row + r2) * N + col] = val;
            }
        }
    }
}

// ---------------------------------------------------------------------------
// RoPE + repack: qkv_bf16 [b,t,3,h,64] -> Qb/Kb [b,h,t,64] (Q pre-scaled by
// 0.125*log2e), Vt [b,h,64,T] with pi key permutation (zero-shuffle PV).
// ---------------------------------------------------------------------------
__global__ __launch_bounds__(256) void rope_pack_k(const u16* __restrict__ qkv,
                                                   const float* __restrict__ cosT,
                                                   const float* __restrict__ sinT,
                                                   u16* __restrict__ Qb,
                                                   u16* __restrict__ Kb,
                                                   u16* __restrict__ Vt) {
    const int t0 = blockIdx.x * 64;
    const int h = blockIdx.y, b = blockIdx.z;
    const int t = threadIdx.x;
    const int bh = b * Hh + h;
    __shared__ u16 Vs[64 * 64];
    constexpr float QSC = 0.125f * 1.44269504089f;   // 1/sqrt(D) * log2(e)

    {
        int row = t >> 2, d16 = (t & 3) * 16;
        const u16* vp = qkv + (size_t)(b * Tt + t0 + row) * 3072 + 2048 + h * 64 + d16;
        *(uint4*)&Vs[row * 64 + d16]     = *(const uint4*)vp;
        *(uint4*)&Vs[row * 64 + d16 + 8] = *(const uint4*)(vp + 8);
    }

    {
        int row = t >> 2, d0 = (t & 3) * 8;
        size_t rb = (size_t)(b * Tt + t0 + row) * 3072 + h * 64;
        const u16* qp = qkv + rb;
        const u16* kp = qkv + rb + 1024;
        Frag8 qlo, qhi, klo, khi;
        qlo.v = *(const uint4*)&qp[d0];
        qhi.v = *(const uint4*)&qp[d0 + 32];
        klo.v = *(const uint4*)&kp[d0];
        khi.v = *(const uint4*)&kp[d0 + 32];
        const float* cp = &cosT[(t0 + row) * 32 + d0];
        const float* sp = &sinT[(t0 + row) * 32 + d0];
        float4 c0 = *(const float4*)cp, c1 = *(const float4*)(cp + 4);
        float4 s0 = *(const float4*)sp, s1 = *(const float4*)(sp + 4);
        float cc[8] = {c0.x, c0.y, c0.z, c0.w, c1.x, c1.y, c1.z, c1.w};
        float ss[8] = {s0.x, s0.y, s0.z, s0.w, s1.x, s1.y, s1.z, s1.w};
        Frag8 oql, oqh, okl, okh;
        #pragma unroll
        for (int i = 0; i < 8; ++i) {
            float ql = bf2f(qlo.u[i]), qh = bf2f(qhi.u[i]);
            float kl = bf2f(klo.u[i]), kh = bf2f(khi.u[i]);
            oql.u[i] = f2bf((ql * cc[i] - qh * ss[i]) * QSC);
            oqh.u[i] = f2bf((qh * cc[i] + ql * ss[i]) * QSC);
            okl.u[i] = f2bf(kl * cc[i] - kh * ss[i]);
            okh.u[i] = f2bf(kh * cc[i] + kl * ss[i]);
        }
        u16* qd = Qb + ((size_t)bh * Tt + t0 + row) * 64;
        u16* kd = Kb + ((size_t)bh * Tt + t0 + row) * 64;
        *(uint4*)&qd[d0]      = oql.v;
        *(uint4*)&qd[d0 + 32] = oqh.v;
        *(uint4*)&kd[d0]      = okl.v;
        *(uint4*)&kd[d0 + 32] = okh.v;
    }
    __syncthreads();

    {
        int d = t >> 2, kq = (t & 3) * 16;
        Frag8 a, b2;
        #pragma unroll
        for (int j = 0; j < 16; ++j) {
            int slot = kq + j;
            int key = ((slot >> 5) * 2 + ((slot >> 2) & 1)) * 16
                    + ((slot >> 3) & 3) * 4 + (slot & 3);
            u16 vv = Vs[key * 64 + d];
            if (j < 8) a.u[j] = vv; else b2.u[j - 8] = vv;
        }
        u16* vd = Vt + ((size_t)bh * 64 + d) * Tt + t0 + kq;
        *(uint4*)&vd[0] = a.v;
        *(uint4*)&vd[8] = b2.v;
    }
}

// ---------------------------------------------------------------------------
// MFMA flash attention v12 (R20 best): K-SPLIT teams. Static-shift softmax
// makes acco/acc_l pure sums over j -> the K-range splits freely. Block = 8
// waves = 2 teams x 4; ONE q-tile c per block; team0 does j in [0,h0),
// team1 [h0,nj). Per-team single-buffered staging (32KB LDS). Cross-team
// partial reduction through LDS at the end. Grid 1024 heavy-first.
// ---------------------------------------------------------------------------
__global__ __launch_bounds__(512) void attn_mfma_k(const u16* __restrict__ Qb,
                                                   const u16* __restrict__ Kb,
                                                   const u16* __restrict__ Vt,
                                                   u16* __restrict__ out) {
    const int i = blockIdx.x;           // 0..1023
    int c, bh;
    if (i < 512) { c = 31 - (i >> 5); bh = i & 31; }        // heavy first
    else         { int k = i - 512; c = k >> 5; bh = k & 31; }
    const int b = bh >> 4, h = bh & 15;

    const int t = threadIdx.x;
    const int w = t >> 6;        // wave 0..7
    const int team = w >> 2;
    const int w4 = w & 3;
    const int l = t & 63;
    const int q15 = l & 15;
    const int g2 = l >> 4;

    __shared__ __align__(16) char lds[32768];
    u16* Ksm = (u16*)(lds + team * 8192);            // [64][64] this team's K
    u16* Vsm = (u16*)(lds + 16384 + team * 8192);    // [64][64] this team's V^T
    float* red = (float*)lds;                        // reduction (20 KB), reused

    const int nj = c + 1;
    const int h0 = (nj + 1) >> 1;
    const int myn = team ? (nj - h0) : h0;
    const int jbase = team ? h0 : 0;

    // ---- Q fragments (exp2-domain scale pre-folded); same q-tile, both teams
    Frag8 qf[2];
    {
        int qrow = c * 64 + w4 * 16 + q15;
        const u16* qp = Qb + ((size_t)bh * Tt + qrow) * 64;
        qf[0] = *(const Frag8*)&qp[g2 * 8];
        qf[1] = *(const Frag8*)&qp[32 + g2 * 8];
    }

    Frag8 ones;
    #pragma unroll
    for (int e = 0; e < 8; ++e) ones.u[e] = 0x3F80;   // bf16 1.0

    f32x4 acco[4];
    #pragma unroll
    for (int dg = 0; dg < 4; ++dg) acco[dg] = (f32x4){0.f, 0.f, 0.f, 0.f};
    f32x4 acc_l = (f32x4){0.f, 0.f, 0.f, 0.f};

    const int srow = l >> 3;
    const int cph = l & 7;
    const int xsw = cph ^ srow;
    const u16* Kbase = Kb + (size_t)bh * Tt * 64;
    const u16* Vbase = Vt + (size_t)bh * 64 * Tt;

    for (int it = 0; it < h0; ++it) {
        __syncthreads();                 // prior compute done (both teams)
        const int j = jbase + it;
        if (it < myn) {
            // ---- stage this team's tile j (single buffer) ----
            #pragma unroll
            for (int iss = 0; iss < 2; ++iss) {
                int rr = w4 * 16 + iss * 8 + srow;
                gload_lds16(Kbase + (size_t)(j * 64 + rr) * 64 + xsw * 8,
                            &Ksm[(w4 * 16 + iss * 8) * 64]);
                gload_lds16(Vbase + (size_t)rr * Tt + j * 64 + xsw * 8,
                            &Vsm[(w4 * 16 + iss * 8) * 64]);
            }
        }
        __syncthreads();                 // staged (vmcnt drained at barrier)
        if (it < myn) {
            // ---- QK^T (swapped): S^T[key][q], log2 domain ----
            f32x4 sacc[4];
            __builtin_amdgcn_s_setprio(1);
            #pragma unroll
            for (int g = 0; g < 4; ++g) {
                sacc[g] = (f32x4){0.f, 0.f, 0.f, 0.f};
                int krow = g * 16 + q15;
                #pragma unroll
                for (int kk = 0; kk < 2; ++kk) {
                    Frag8 kf = *(const Frag8*)&Ksm[krow * 64 + (((kk * 4 + g2) ^ (krow & 7)) * 8)];
                    sacc[g] = __builtin_amdgcn_mfma_f32_16x16x32_bf16(
                        kf.b, qf[kk].b, sacc[g], 0, 0, 0);
                }
            }
            __builtin_amdgcn_s_setprio(0);
            if (j == c) {   // diagonal tile: causal mask (true key order)
                #pragma unroll
                for (int g = 0; g < 4; ++g)
                    #pragma unroll
                    for (int r = 0; r < 4; ++r)
                        if (g * 16 + g2 * 4 + r > w4 * 16 + q15) sacc[g][r] = -1e30f;
            }

            // ---- P = exp2(S) straight into PV A-fragments (pi-Vt) ----
            Frag8 pa[2];
            #pragma unroll
            for (int kk = 0; kk < 2; ++kk)
                #pragma unroll
                for (int e = 0; e < 8; ++e)
                    pa[kk].b[e] = (__bf16)exp2f(sacc[2 * kk + (e >> 2)][e & 3]);

            // ---- l-sum + PV ----
            __builtin_amdgcn_s_setprio(1);
            acc_l = __builtin_amdgcn_mfma_f32_16x16x32_bf16(pa[0].b, ones.b, acc_l, 0, 0, 0);
            acc_l = __builtin_amdgcn_mfma_f32_16x16x32_bf16(pa[1].b, ones.b, acc_l, 0, 0, 0);
            #pragma unroll
            for (int dg = 0; dg < 4; ++dg) {
                int vrow = dg * 16 + q15;
                #pragma unroll
                for (int kk = 0; kk < 2; ++kk) {
                    Frag8 vf = *(const Frag8*)&Vsm[vrow * 64 + (((kk * 4 + g2) ^ (vrow & 7)) * 8)];
                    acco[dg] = __builtin_amdgcn_mfma_f32_16x16x32_bf16(
                        pa[kk].b, vf.b, acco[dg], 0, 0, 0);
                }
            }
            __builtin_amdgcn_s_setprio(0);
        }
    }

    // ---- cross-team reduction: team1 -> LDS, team0 adds + epilogue ----
    __syncthreads();
    const int slot = (w4 * 64 + l) * 20;
    if (team == 1) {
        #pragma unroll
        for (int dg = 0; dg < 4; ++dg)
            #pragma unroll
            for (int r = 0; r < 4; ++r) red[slot + dg * 4 + r] = acco[dg][r];
        #pragma unroll
        for (int r = 0; r < 4; ++r) red[slot + 16 + r] = acc_l[r];
    }
    __syncthreads();
    if (team == 0) {
        #pragma unroll
        for (int dg = 0; dg < 4; ++dg)
            #pragma unroll
            for (int r = 0; r < 4; ++r) acco[dg][r] += red[slot + dg * 4 + r];
        #pragma unroll
        for (int r = 0; r < 4; ++r) acc_l[r] += red[slot + 16 + r];

        float lr[4];
        #pragma unroll
        for (int r = 0; r < 4; ++r) lr[r] = 1.f / acc_l[r];
        const int qbase = c * 64 + w4 * 16;
        #pragma unroll
        for (int dg = 0; dg < 4; ++dg)
            #pragma unroll
            for (int r = 0; r < 4; ++r)
                out[((size_t)(b * Tt + qbase + g2 * 4 + r)) * Cc + h * 64 + dg * 16 + q15] =
                    f2bf(acco[dg][r] * lr[r]);
    }
}

// ---------------------------------------------------------------------------
// Launch
// ---------------------------------------------------------------------------
extern "C" void kernel_launch(void* const* d_in, const int* in_sizes, int n_in,
                              void* d_out, int out_size, void* d_ws, size_t ws_size,
                              hipStream_t stream) {
    const float* x      = (const float*)d_in[0];
    const float* w_qkv  = (const float*)d_in[2];
    const float* b_qkv  = (const float*)d_in[3];
    const float* w_o    = (const float*)d_in[4];
    const float* b_o    = (const float*)d_in[5];
    const float* rms_w  = (const float*)d_in[6];
    float* out = (float*)d_out;

    char* ws = (char*)d_ws;
    u16*   xn_bf   = (u16*)ws;                                   // 8 MB [0,8)
    u16*   Kb      = (u16*)(ws + (size_t)(8 << 20));             // 8 MB [8,16)
    u16*   Vt      = (u16*)(ws + (size_t)(16 << 20));            // 8 MB [16,24)
    u16*   Qb      = (u16*)(ws + (size_t)(24 << 20));            // 8 MB [24,32)
    u16*   qkvb    = (u16*)(ws + (size_t)(32 << 20));            // 24 MB [32,56)
    u16*   wqkv_bf = (u16*)(ws + (size_t)(56 << 20));            // 6 MB [56,62)
    u16*   wo_bf   = (u16*)(ws + (size_t)(62 << 20));            // 2 MB [62,64)
    float* cosT    = (float*)(ws + (size_t)(64 << 20));          // 256 KB
    float* sinT    = (float*)(ws + (size_t)(64 << 20) + (1 << 18));
    u16*   attn_bf = xn_bf;   // xn dead after QKV GEMM

    prep_k<<<dim3(8448), dim3(256), 0, stream>>>(w_qkv, wqkv_bf, w_o, wo_bf,
                                                 cosT, sinT, x, rms_w, xn_bf);
    gemm_mfma_k<true><<<dim3(3 * Cc / 64, M_ROWS / 128), dim3(256), 0, stream>>>(
        xn_bf, wqkv_bf, b_qkv, qkvb, M_ROWS, 3 * Cc, Cc);
    rope_pack_k<<<dim3(Tt / 64, Hh, Bb), dim3(256), 0, stream>>>(
        qkvb, cosT, sinT, Qb, Kb, Vt);
    attn_mfma_k<<<dim3(1024), dim3(512), 0, stream>>>(Qb, Kb, Vt, attn_bf);
    gemm_mfma_k<false><<<dim3(Cc / 64, M_ROWS / 128), dim3(256), 0, stream>>>(
        attn_bf, wo_bf, b_o, out, M_ROWS, Cc, Cc);
}